// Round 6
// baseline (110.606 us; speedup 1.0000x reference)
//
#include <hip/hip_runtime.h>
#include <math.h>

// Problem constants (fixed by the reference's setup_inputs)
#define CLS 2
#define BATCH 8
#define HH 512
#define WW 512
#define INV_SCALE 0.125f
#define LOGEPS -16.118095651f   // log(1e-7)

#define NB 128       // atomic buckets per quantity
#define TSTRIDE 192  // per-batch SoA stride (capacity; nT<=160 total)
#define TCAP 192     // LDS compacted-target capacity
#define NBLK 8192    // (BATCH*HH*WW)/256
#define LEAFQ (NBLK / 64)   // blocks per leaf counter = 128

// ws layout:
//   double gsum[4][NB]            @ 0      (4096 B) obj_c0, obj_c1, noobj_c0, noobj_c1
//   int    gcnt[4][NB]            @ 4096   (2048 B)
//   int    leaf[64]               @ 6144   ( 256 B)
//   int    root                   @ 6400   (   4 B)
//   int    bcnt[8]                @ 6432   (  32 B)
//   float  tdat[8][7][TSTRIDE]    @ 6464   (43008 B) cs,sn,x3,x4,y3,y4,cid per batch

__global__ __launch_bounds__(256) void heatmap_prep(
    const float* __restrict__ targets, int nT, double* __restrict__ gsum,
    int* __restrict__ gcnt, int* __restrict__ leafroot,
    int* __restrict__ bcnt, float* __restrict__ tdat)
{
    __shared__ int s_b[BATCH];
    const int t = threadIdx.x;
    if (t < BATCH) s_b[t] = 0;
    for (int q = t; q < 4 * NB; q += 256) { gsum[q] = 0.0; gcnt[q] = 0; }
    if (t < 65) leafroot[t] = 0;      // leaf[64] + root
    __syncthreads();
    if (t < nT) {
        const float* tp = targets + t * 7;
        const int b = (int)tp[0];
        const float cs = cosf(tp[6]), sn = sinf(tp[6]);
        const float cx = tp[2] * INV_SCALE, cy = tp[3] * INV_SCALE;
        const float w_ = tp[4] * INV_SCALE, h_ = tp[5] * INV_SCALE;
        const float x = cx * cs + cy * sn;
        const float y = -cx * sn + cy * cs;
        const int slot = atomicAdd(&s_b[b], 1);
        float* tb = tdat + b * (7 * TSTRIDE);
        tb[0 * TSTRIDE + slot] = cs;
        tb[1 * TSTRIDE + slot] = sn;
        tb[2 * TSTRIDE + slot] = x - 0.5f * h_;
        tb[3 * TSTRIDE + slot] = x + 0.5f * h_;
        tb[4 * TSTRIDE + slot] = y - 0.5f * w_;
        tb[5 * TSTRIDE + slot] = y + 0.5f * w_;
        ((int*)tb)[6 * TSTRIDE + slot] = (int)tp[1];
    }
    __syncthreads();
    if (t < BATCH) bcnt[t] = s_b[t];
}

// 64 threads/block (1 wave), 4 contiguous px/thread, 256-px row strip per block.
// Finalize fused via leaf[64]->root done counters (no per-block fence).
__global__ __launch_bounds__(64) void heatmap_main(
    const float* __restrict__ predict, float* __restrict__ out,
    double* __restrict__ gsum, int* __restrict__ gcnt,
    int* __restrict__ leaf, int* __restrict__ root,
    const int* __restrict__ bcnt, const float* __restrict__ tdat)
{
    __shared__ float s_cs[TCAP], s_sn[TCAP];
    __shared__ float s_x3[TCAP], s_x4[TCAP], s_y3[TCAP], s_y4[TCAP];
    __shared__ int   s_cid[TCAP];

    const int l = threadIdx.x;
    const int blockPix = blockIdx.x * 256;
    const int b  = blockPix >> 18;             // / (H*W)
    const int i  = (blockPix >> 9) & (HH - 1); // row
    const int j0 = blockPix & (WW - 1);        // 0 or 256
    const float gy = (float)i + 0.5f;

    // --- compaction from per-batch prepped SoA: ballot-prefix, no atomics ---
    const int nb = bcnt[b];
    const float* tb = tdat + b * (7 * TSTRIDE);
    int cnt = 0;
    for (int base = 0; base < nb; base += 64) {
        bool acc = false;
        float cs = 0.f, sn = 0.f, x3 = 0.f, x4 = 0.f, y3 = 0.f, y4 = 0.f;
        int cid = 0;
        const int t = base + l;
        if (t < nb) {
            cs = tb[0 * TSTRIDE + t]; sn = tb[1 * TSTRIDE + t];
            x3 = tb[2 * TSTRIDE + t]; x4 = tb[3 * TSTRIDE + t];
            y3 = tb[4 * TSTRIDE + t]; y4 = tb[5 * TSTRIDE + t];
            cid = ((const int*)tb)[6 * TSTRIDE + t];
            // strip: gx in [j0+0.5, j0+255.5], gy fixed -> exact vx/vy intervals
            const float gxl = (float)j0 + 0.5f, gxh = (float)j0 + 255.5f;
            const float a1 = cs * gxl + sn * gy, a2 = cs * gxh + sn * gy;
            const float b1 = -sn * gxl + cs * gy, b2 = -sn * gxh + cs * gy;
            const float vxlo = fminf(a1, a2), vxhi = fmaxf(a1, a2);
            const float vylo = fminf(b1, b2), vyhi = fmaxf(b1, b2);
            const float M = 0.51f; // outer margin 0.5 + fp slack
            acc = (vxhi >= x3 - M) & (vxlo <= x4 + M) &
                  (vyhi >= y3 - M) & (vylo <= y4 + M);
        }
        const unsigned long long bal = __ballot(acc);
        if (acc) {
            const int slot = cnt + (int)__popcll(bal & ((1ull << l) - 1ull));
            s_cs[slot] = cs; s_sn[slot] = sn;
            s_x3[slot] = x3; s_x4[slot] = x4;
            s_y3[slot] = y3; s_y4[slot] = y4;
            s_cid[slot] = cid;
        }
        cnt += (int)__popcll(bal);
    }
    __syncthreads();  // single wave: orders LDS writes before reads

    // --- masks for 4 contiguous pixels (vx,vy incremental along gx) ---
    const int j = j0 + 4 * l;
    const float gxb = (float)j + 0.5f;
    int objm[4] = {0, 0, 0, 0}, outm[4] = {0, 0, 0, 0};
    for (int n = 0; n < cnt; ++n) {      // cnt is wave-uniform; usually 0
        const float cs = s_cs[n], sn = s_sn[n];
        const float x3 = s_x3[n], x4 = s_x4[n], y3 = s_y3[n], y4 = s_y4[n];
        const int cbit = 1 << s_cid[n];
        float vx = cs * gxb + sn * gy;
        float vy = -sn * gxb + cs * gy;
        #pragma unroll
        for (int k = 0; k < 4; ++k) {
            const bool in_  = (x3 <= vx) & (vx <= x4) & (y3 <= vy) & (vy <= y4);
            const bool out_ = (x3 - 0.5f <= vx) & (vx <= x4 + 0.5f) &
                              (y3 - 0.5f <= vy) & (vy <= y4 + 0.5f);
            if (in_)  objm[k] |= cbit;
            if (out_) outm[k] |= cbit;
            vx += cs; vy -= sn;
        }
    }

    // --- vectorized loads; sigmoid/log algebra (5 transcendentals/px) ---
    const int pbase = (b * CLS * HH + i) * WW + j;   // 16B-aligned (j = 4l)
    const float4 P0 = *(const float4*)(predict + pbase);
    const float4 P1 = *(const float4*)(predict + pbase + HH * WW);

    float so0 = 0.f, so1 = 0.f, sq0 = 0.f, sq1 = 0.f;
    int c_obj0 = 0, c_obj1 = 0, c_no0 = 0, c_no1 = 0;
    float hm[4];
    #pragma unroll
    for (int k = 0; k < 4; ++k) {
        const float p0 = (&P0.x)[k], p1 = (&P1.x)[k];
        const float t0 = __expf(p0), t1 = __expf(p1);
        const float l0n = -__logf(1.0f + t0);   // log(1-conf0)
        const float l1n = -__logf(1.0f + t1);
        const float lc0 = fmaxf(p0 + l0n, LOGEPS);  // log(conf0), EPS-clipped
        const float lc1 = fmaxf(p1 + l1n, LOGEPS);
        const float l0c = fmaxf(l0n, LOGEPS);
        const float l1c = fmaxf(l1n, LOGEPS);
        const float tm = fmaxf(t0, t1);
        hm[k] = tm * __builtin_amdgcn_rcpf(1.0f + tm);  // sigmoid(max(p0,p1))
        const int om = objm[k], um = outm[k];
        if (om & 1) { so0 += lc0; ++c_obj0; }
        if (om & 2) { so1 += lc1; ++c_obj1; }
        if (!(um & 1)) { sq0 += l0c; ++c_no0; }
        if (!(um & 2)) { sq1 += l1c; ++c_no1; }
    }

    float* ho = out + 1 + (b * HH + i) * WW + j;  // +1 -> only 4B-aligned
    __builtin_memcpy(ho, hm, 16);

    // --- wave reduction; obj trees skipped wave-uniformly when empty ---
    const unsigned long long anyobj =
        __ballot((objm[0] | objm[1] | objm[2] | objm[3]) != 0);
    int pc = (c_no0 & 0xffff) | (c_no1 << 16);
    #pragma unroll
    for (int off = 32; off >= 1; off >>= 1) {
        sq0 += __shfl_down(sq0, off);
        sq1 += __shfl_down(sq1, off);
        pc  += __shfl_down(pc, off);
    }
    int po = 0;
    if (anyobj) {
        po = (c_obj0 & 0xffff) | (c_obj1 << 16);
        #pragma unroll
        for (int off = 32; off >= 1; off >>= 1) {
            so0 += __shfl_down(so0, off);
            so1 += __shfl_down(so1, off);
            po  += __shfl_down(po, off);
        }
    }

    int isLast = 0;
    if (l == 0) {
        const int bkt = blockIdx.x & (NB - 1);
        atomicAdd(&gsum[2 * NB + bkt], (double)sq0);
        atomicAdd(&gsum[3 * NB + bkt], (double)sq1);
        atomicAdd(&gcnt[2 * NB + bkt], pc & 0xffff);
        atomicAdd(&gcnt[3 * NB + bkt], pc >> 16);
        if (anyobj) {
            const int o0 = po & 0xffff, o1 = po >> 16;
            if (o0) { atomicAdd(&gsum[0 * NB + bkt], (double)so0);
                      atomicAdd(&gcnt[0 * NB + bkt], o0); }
            if (o1) { atomicAdd(&gsum[1 * NB + bkt], (double)so1);
                      atomicAdd(&gcnt[1 * NB + bkt], o1); }
        }
        // order: bucket atomics complete before counter atomics
        asm volatile("s_waitcnt vmcnt(0)" ::: "memory");
        const int lv = atomicAdd(&leaf[blockIdx.x & 63], 1);  // returned value
        if (lv == LEAFQ - 1) {                 // value dep => add completed
            const int rv = atomicAdd(root, 1);
            if (rv == 63) isLast = 1;
        }
    }
    isLast = __shfl(isLast, 0);

    // --- fused finalize: last block reduces buckets via coherent RMW reads ---
    if (isLast) {
        double f[4] = {0, 0, 0, 0}; int c[4] = {0, 0, 0, 0};
        for (int t = l; t < NB; t += 64) {
            #pragma unroll
            for (int q = 0; q < 4; ++q) {
                f[q] += atomicAdd(&gsum[q * NB + t], 0.0);
                c[q] += atomicAdd(&gcnt[q * NB + t], 0);
            }
        }
        #pragma unroll
        for (int off = 32; off >= 1; off >>= 1) {
            #pragma unroll
            for (int q = 0; q < 4; ++q) {
                f[q] += __shfl_down(f[q], off);
                c[q] += __shfl_down(c[q], off);
            }
        }
        if (l == 0) {
            float loss = 0.0f;
            #pragma unroll
            for (int cls = 0; cls < CLS; ++cls) {
                const int no = c[cls];
                const int nn = c[2 + cls];
                if (no > 0) {
                    const float lo  = -(float)f[cls]     / (float)(no > 1 ? no : 1);
                    const float ln_ = -(float)f[2 + cls] / (float)(nn > 1 ? nn : 1);
                    loss += lo + ln_;  // NO_OBJ_SCALE = 1.0
                }
            }
            out[0] = loss;
        }
    }
}

extern "C" void kernel_launch(void* const* d_in, const int* in_sizes, int n_in,
                              void* d_out, int out_size, void* d_ws, size_t ws_size,
                              hipStream_t stream) {
    const float* predict = (const float*)d_in[0];
    const float* targets = (const float*)d_in[1];
    const int nT = in_sizes[1] / 7;
    float* out = (float*)d_out;
    char* ws = (char*)d_ws;
    double* gsum = (double*)ws;
    int* gcnt = (int*)(ws + 4096);
    int* leaf = (int*)(ws + 6144);
    int* root = (int*)(ws + 6400);
    int* bcnt = (int*)(ws + 6432);
    float* tdat = (float*)(ws + 6464);

    heatmap_prep<<<1, 256, 0, stream>>>(targets, nT, gsum, gcnt, leaf, bcnt,
                                        tdat);
    heatmap_main<<<NBLK, 64, 0, stream>>>(predict, out, gsum, gcnt, leaf, root,
                                          bcnt, tdat);
}

// Round 7
// 80.431 us; speedup vs baseline: 1.3752x; 1.3752x over previous
//
#include <hip/hip_runtime.h>
#include <math.h>

// Problem constants (fixed by the reference's setup_inputs)
#define CLS 2
#define BATCH 8
#define HH 512
#define WW 512
#define INV_SCALE 0.125f
#define LOGEPS -16.118095651f   // log(1e-7)

#define NB 512       // atomic buckets per quantity
#define TSTRIDE 192  // per-batch SoA stride (capacity; nT<=160 total)

// ws layout:
//   double gsum[4][NB]            @ 0      (16384 B) obj_c0, obj_c1, noobj_c0, noobj_c1
//   int    gcnt[4][NB]            @ 16384  ( 8192 B)
//   int    bcnt[8]                @ 24576  (   32 B)
//   float  tdat[8][7][TSTRIDE]    @ 24608  (43008 B) cs,sn,x3,x4,y3,y4,cid per batch

__global__ __launch_bounds__(256) void heatmap_prep(
    const float* __restrict__ targets, int nT, double* __restrict__ gsum,
    int* __restrict__ gcnt, int* __restrict__ bcnt, float* __restrict__ tdat)
{
    __shared__ int s_b[BATCH];
    const int t = threadIdx.x;
    if (t < BATCH) s_b[t] = 0;
    for (int q = t; q < 4 * NB; q += 256) { gsum[q] = 0.0; gcnt[q] = 0; }
    __syncthreads();
    if (t < nT) {
        const float* tp = targets + t * 7;
        const int b = (int)tp[0];
        const float cs = cosf(tp[6]), sn = sinf(tp[6]);
        const float cx = tp[2] * INV_SCALE, cy = tp[3] * INV_SCALE;
        const float w_ = tp[4] * INV_SCALE, h_ = tp[5] * INV_SCALE;
        const float x = cx * cs + cy * sn;
        const float y = -cx * sn + cy * cs;
        const int slot = atomicAdd(&s_b[b], 1);
        float* tbp = tdat + b * (7 * TSTRIDE);
        tbp[0 * TSTRIDE + slot] = cs;
        tbp[1 * TSTRIDE + slot] = sn;
        tbp[2 * TSTRIDE + slot] = x - 0.5f * h_;
        tbp[3 * TSTRIDE + slot] = x + 0.5f * h_;
        tbp[4 * TSTRIDE + slot] = y - 0.5f * w_;
        tbp[5 * TSTRIDE + slot] = y + 0.5f * w_;
        ((int*)tbp)[6 * TSTRIDE + slot] = (int)tp[1];
    }
    __syncthreads();
    if (t < BATCH) bcnt[t] = s_b[t];
}

// 256 threads = 4 INDEPENDENT waves; each wave owns one 256-px row strip.
// No LDS, no __syncthreads: target params broadcast in-register via shfl.
__global__ __launch_bounds__(256) void heatmap_main(
    const float* __restrict__ predict, float* __restrict__ out,
    double* __restrict__ gsum, int* __restrict__ gcnt,
    const int* __restrict__ bcnt, const float* __restrict__ tdat)
{
    const int wid = threadIdx.x >> 6;
    const int l   = threadIdx.x & 63;
    const int sidx = blockIdx.x * 4 + wid;     // strip index 0..8191
    const int blockPix = sidx * 256;
    const int b  = blockPix >> 18;              // / (H*W)
    const int i  = (blockPix >> 9) & (HH - 1);  // row
    const int j0 = blockPix & (WW - 1);         // 0 or 256
    const float gy = (float)i + 0.5f;

    const int j = j0 + 4 * l;
    const float gxb = (float)j + 0.5f;

    const int nb = bcnt[b];
    const float* tbp = tdat + b * (7 * TSTRIDE);

    int objm[4] = {0, 0, 0, 0}, outm[4] = {0, 0, 0, 0};

    for (int base = 0; base < nb; base += 64) {
        const int t = base + l;
        float cs = 0.f, sn = 0.f, x3 = 0.f, x4 = 0.f, y3 = 0.f, y4 = 0.f;
        int cid = 0;
        bool acc = false;
        if (t < nb) {
            cs = tbp[0 * TSTRIDE + t]; sn = tbp[1 * TSTRIDE + t];
            x3 = tbp[2 * TSTRIDE + t]; x4 = tbp[3 * TSTRIDE + t];
            y3 = tbp[4 * TSTRIDE + t]; y4 = tbp[5 * TSTRIDE + t];
            cid = ((const int*)tbp)[6 * TSTRIDE + t];
            // strip: gx in [j0+0.5, j0+255.5], gy fixed -> exact vx/vy intervals
            const float gxl = (float)j0 + 0.5f, gxh = (float)j0 + 255.5f;
            const float a1 = cs * gxl + sn * gy, a2 = cs * gxh + sn * gy;
            const float b1 = -sn * gxl + cs * gy, b2 = -sn * gxh + cs * gy;
            const float vxlo = fminf(a1, a2), vxhi = fmaxf(a1, a2);
            const float vylo = fminf(b1, b2), vyhi = fmaxf(b1, b2);
            const float M = 0.51f;  // outer margin 0.5 + fp slack
            acc = (vxhi >= x3 - M) & (vxlo <= x4 + M) &
                  (vyhi >= y3 - M) & (vylo <= y4 + M);
        }
        unsigned long long bal = __ballot(acc);   // wave-uniform hit mask
        while (bal) {
            const int n = __builtin_ctzll(bal);   // uniform lane index
            bal &= bal - 1;
            const float ccs = __shfl(cs, n), csn = __shfl(sn, n);
            const float cx3 = __shfl(x3, n), cx4 = __shfl(x4, n);
            const float cy3 = __shfl(y3, n), cy4 = __shfl(y4, n);
            const int cbit = 1 << __shfl(cid, n);
            float vx = ccs * gxb + csn * gy;
            float vy = -csn * gxb + ccs * gy;
            #pragma unroll
            for (int k = 0; k < 4; ++k) {
                const bool in_  = (cx3 <= vx) & (vx <= cx4) &
                                  (cy3 <= vy) & (vy <= cy4);
                const bool out_ = (cx3 - 0.5f <= vx) & (vx <= cx4 + 0.5f) &
                                  (cy3 - 0.5f <= vy) & (vy <= cy4 + 0.5f);
                if (in_)  objm[k] |= cbit;
                if (out_) outm[k] |= cbit;
                vx += ccs; vy -= csn;
            }
        }
    }

    // --- vectorized loads; sigmoid/log algebra (5 transcendentals/px) ---
    const int pbase = (b * CLS * HH + i) * WW + j;   // 16B-aligned (j = 4l)
    const float4 P0 = *(const float4*)(predict + pbase);
    const float4 P1 = *(const float4*)(predict + pbase + HH * WW);

    float so0 = 0.f, so1 = 0.f, sq0 = 0.f, sq1 = 0.f;
    int c_obj0 = 0, c_obj1 = 0, c_no0 = 0, c_no1 = 0;
    float hm[4];
    #pragma unroll
    for (int k = 0; k < 4; ++k) {
        const float p0 = (&P0.x)[k], p1 = (&P1.x)[k];
        const float t0 = __expf(p0), t1 = __expf(p1);
        const float l0n = -__logf(1.0f + t0);       // log(1-conf0)
        const float l1n = -__logf(1.0f + t1);
        const float lc0 = fmaxf(p0 + l0n, LOGEPS);  // log(conf0), EPS-clipped
        const float lc1 = fmaxf(p1 + l1n, LOGEPS);
        const float l0c = fmaxf(l0n, LOGEPS);
        const float l1c = fmaxf(l1n, LOGEPS);
        const float tm = fmaxf(t0, t1);
        hm[k] = tm * __builtin_amdgcn_rcpf(1.0f + tm);  // sigmoid(max(p0,p1))
        const int om = objm[k], um = outm[k];
        if (om & 1) { so0 += lc0; ++c_obj0; }
        if (om & 2) { so1 += lc1; ++c_obj1; }
        if (!(um & 1)) { sq0 += l0c; ++c_no0; }
        if (!(um & 2)) { sq1 += l1c; ++c_no1; }
    }

    float* ho = out + 1 + (b * HH + i) * WW + j;  // +1: misaligned -> 4 dwords
    ho[0] = hm[0]; ho[1] = hm[1]; ho[2] = hm[2]; ho[3] = hm[3];

    // --- wave reduction; obj trees skipped wave-uniformly when empty ---
    const unsigned long long anyobj =
        __ballot((objm[0] | objm[1] | objm[2] | objm[3]) != 0);
    int pc = (c_no0 & 0xffff) | (c_no1 << 16);
    #pragma unroll
    for (int off = 32; off >= 1; off >>= 1) {
        sq0 += __shfl_down(sq0, off);
        sq1 += __shfl_down(sq1, off);
        pc  += __shfl_down(pc, off);
    }
    int po = 0;
    if (anyobj) {
        po = (c_obj0 & 0xffff) | (c_obj1 << 16);
        #pragma unroll
        for (int off = 32; off >= 1; off >>= 1) {
            so0 += __shfl_down(so0, off);
            so1 += __shfl_down(so1, off);
            po  += __shfl_down(po, off);
        }
    }
    if (l == 0) {
        const int bkt = sidx & (NB - 1);
        atomicAdd(&gsum[2 * NB + bkt], (double)sq0);
        atomicAdd(&gsum[3 * NB + bkt], (double)sq1);
        atomicAdd(&gcnt[2 * NB + bkt], pc & 0xffff);
        atomicAdd(&gcnt[3 * NB + bkt], pc >> 16);
        if (anyobj) {
            const int o0 = po & 0xffff, o1 = po >> 16;
            if (o0) { atomicAdd(&gsum[0 * NB + bkt], (double)so0);
                      atomicAdd(&gcnt[0 * NB + bkt], o0); }
            if (o1) { atomicAdd(&gsum[1 * NB + bkt], (double)so1);
                      atomicAdd(&gcnt[1 * NB + bkt], o1); }
        }
    }
}

__global__ __launch_bounds__(512) void heatmap_finalize(
    const double* __restrict__ gsum, const int* __restrict__ gcnt,
    float* __restrict__ out)
{
    const int t = threadIdx.x;          // 0..511 == one bucket each
    double f[4]; int c[4];
    #pragma unroll
    for (int q = 0; q < 4; ++q) { f[q] = gsum[q * NB + t]; c[q] = gcnt[q * NB + t]; }

    #pragma unroll
    for (int off = 32; off >= 1; off >>= 1) {
        #pragma unroll
        for (int q = 0; q < 4; ++q) {
            f[q] += __shfl_down(f[q], off);
            c[q] += __shfl_down(c[q], off);
        }
    }

    __shared__ double sf[8][4];
    __shared__ int    si[8][4];
    const int wv = t >> 6, ln = t & 63;
    if (ln == 0) {
        #pragma unroll
        for (int q = 0; q < 4; ++q) { sf[wv][q] = f[q]; si[wv][q] = c[q]; }
    }
    __syncthreads();
    if (t == 0) {
        double F[4] = {0, 0, 0, 0}; int C[4] = {0, 0, 0, 0};
        for (int w = 0; w < 8; ++w)
            #pragma unroll
            for (int q = 0; q < 4; ++q) { F[q] += sf[w][q]; C[q] += si[w][q]; }
        float loss = 0.0f;
        #pragma unroll
        for (int cls = 0; cls < CLS; ++cls) {
            const int no = C[cls];
            const int nn = C[2 + cls];
            if (no > 0) {
                const float lo  = -(float)F[cls]     / (float)(no > 1 ? no : 1);
                const float ln_ = -(float)F[2 + cls] / (float)(nn > 1 ? nn : 1);
                loss += lo + ln_;  // NO_OBJ_SCALE = 1.0
            }
        }
        out[0] = loss;
    }
}

extern "C" void kernel_launch(void* const* d_in, const int* in_sizes, int n_in,
                              void* d_out, int out_size, void* d_ws, size_t ws_size,
                              hipStream_t stream) {
    const float* predict = (const float*)d_in[0];
    const float* targets = (const float*)d_in[1];
    const int nT = in_sizes[1] / 7;
    float* out = (float*)d_out;
    char* ws = (char*)d_ws;
    double* gsum = (double*)ws;
    int* gcnt = (int*)(ws + 16384);
    int* bcnt = (int*)(ws + 24576);
    float* tdat = (float*)(ws + 24608);

    heatmap_prep<<<1, 256, 0, stream>>>(targets, nT, gsum, gcnt, bcnt, tdat);
    const int nstrips = BATCH * HH * WW / 256;   // 8192
    heatmap_main<<<nstrips / 4, 256, 0, stream>>>(predict, out, gsum, gcnt,
                                                  bcnt, tdat);
    heatmap_finalize<<<1, 512, 0, stream>>>(gsum, gcnt, out);
}